// Round 3
// baseline (359.596 us; speedup 1.0000x reference)
//
#include <hip/hip_runtime.h>
#include <math.h>

#define BATCH 16
#define NN 25200
#define NCLS 80
#define K_PRE 1024
#define MAX_DET 300
#define CONF_T 0.4f
#define IOU_T 0.45f
#define TBIAS 0x3E000000u
// key layout (47 bits): t(25) << 22 | (NN-1-n)(15) << 7 | cls(7)
// (t, n) is unique, so cls in the low bits never affects sort order.
#define RROWS 128
#define STHREADS 512

// ---------------------------------------------------------------------------
// K1: LDS-staged score + argmax -> 64-bit sort key per row. Pure streaming:
// reads the full 137 MB pred once, coalesced float4. No histogram here any
// more (moved into the fused kernel; keys are L2-resident there).
// ---------------------------------------------------------------------------
__global__ void __launch_bounds__(STHREADS) score_kernel(
    const float* __restrict__ pred, unsigned long long* __restrict__ keys) {
    __shared__ float srow[RROWS * 85];

    const int tile = blockIdx.x, b = blockIdx.y, tid = threadIdx.x;
    const int row0 = tile * RROWS;
    int nrows = NN - row0;
    if (nrows > RROWS) nrows = RROWS;

    const float4* g4 = (const float4*)(pred + ((size_t)b * NN + row0) * 85);
    float4* l4 = (float4*)srow;
    const int nf4 = (nrows * 85) >> 2;  // nrows % 4 == 0 always
    for (int i = tid; i < nf4; i += STHREADS) l4[i] = g4[i];
    __syncthreads();

    const int r = tid >> 2, sub = tid & 3;
    float best = 0.0f;
    int bc = sub * 20;
    float obj = 0.0f;
    if (r < nrows) {
        obj = srow[r * 85 + 4];
        if (obj > CONF_T) {
            const float* cp = &srow[r * 85 + 5 + sub * 20];
#pragma unroll
            for (int i = 0; i < 20; ++i) {
                float v = cp[i] * obj;
                if (v > best) { best = v; bc = sub * 20 + i; }  // first-max
            }
        }
    }
    // reduce (best, bc) across the 4 lanes of this row, first-max semantics
#pragma unroll
    for (int d = 1; d < 4; d <<= 1) {
        float ov = __shfl_xor(best, d);
        int oc = __shfl_xor(bc, d);
        if (ov > best || (ov == best && oc < bc)) { best = ov; bc = oc; }
    }
    if (r < nrows && sub == 0) {
        unsigned t = (obj > CONF_T && best > CONF_T)
                         ? (__float_as_uint(best) - TBIAS) : 0u;
        int n = row0 + r;
        keys[(size_t)b * NN + n] =
            ((unsigned long long)t << 22) |
            ((unsigned long long)(unsigned)(NN - 1 - n) << 7) | (unsigned)bc;
    }
}

// ---------------------------------------------------------------------------
// K2 (fused): per batch — radix hist + digit select + compact + bitonic-2048
// sort + prep (LDS SoA) + per-class NMS (wave per class, register bitmask
// greedy) + rank scan + output write with tail zero-fill. All candidate
// state stays in LDS; nothing round-trips through global memory.
// ---------------------------------------------------------------------------
__global__ void __launch_bounds__(1024) fused_kernel(
    const unsigned long long* __restrict__ keys,
    const float* __restrict__ pred,
    const float* __restrict__ conf_logits,
    const float* __restrict__ logits,
    const float* __restrict__ head,
    float* __restrict__ out) {
    __shared__ unsigned sA[1024], sB[1024];           // hist / scan ping-pong
    __shared__ unsigned long long skeys[2048];        // 16 KB
    __shared__ float bx0[K_PRE], by0[K_PRE], bx1[K_PRE], by1[K_PRE],
        bar_[K_PRE], bsc[K_PRE];                      // 24 KB box SoA
    __shared__ unsigned char bcls[K_PRE];             // class (255 = invalid)
    __shared__ unsigned short bgi[K_PRE];             // original row n
    __shared__ unsigned char bkeep[K_PRE];
    __shared__ unsigned sel_d0, sel_cnt;

    const int b = blockIdx.x, tid = threadIdx.x;
    const unsigned long long* bk = keys + (size_t)b * NN;

    // ---- pass 1: 10-bit digit histogram of valid keys (keys are L2-hot) ----
    sA[tid] = 0u;
    __syncthreads();
    for (int base = 0; base < 25600; base += 1024) {
        int i = base + tid;
        if (i < NN) {
            unsigned t = (unsigned)(bk[i] >> 22);
            if (t) atomicAdd(&sA[t >> 15], 1u);
        }
    }
    __syncthreads();

    // ---- suffix-inclusive scan of the histogram ----
    unsigned* src = sA;
    unsigned* dst = sB;
    for (int off = 1; off < 1024; off <<= 1) {
        dst[tid] = src[tid] + ((tid + off < 1024) ? src[tid + off] : 0u);
        __syncthreads();
        unsigned* t2 = src; src = dst; dst = t2;
    }
    unsigned total = src[0];
    unsigned K = total < 1024u ? total : 1024u;
    if (tid == 0) { sel_d0 = 0u; sel_cnt = 0u; }
    skeys[tid] = 0ull;
    skeys[tid + 1024] = 0ull;
    __syncthreads();
    if (total) {
        unsigned geq = src[tid];
        unsigned gt = (tid < 1023) ? src[tid + 1] : 0u;
        if (gt < K && K <= geq) sel_d0 = (unsigned)tid;  // unique writer
    }
    __syncthreads();
    const unsigned d0 = sel_d0;

    // ---- pass 2: compact keys with digit >= d0 (~K + one bucket) ----
    for (int base = 0; base < 25600; base += 1024) {
        int i = base + tid;
        if (i < NN) {
            unsigned long long key = bk[i];
            unsigned t = (unsigned)(key >> 22);
            if (t && (t >> 15) >= d0) {
                unsigned p = atomicAdd(&sel_cnt, 1u);
                if (p < 2048u) skeys[p] = key;
            }
        }
    }
    __syncthreads();

    // ---- bitonic sort 2048 descending; thread owns pair (i, i|j) ----
    for (unsigned k2 = 2; k2 <= 2048; k2 <<= 1) {
        for (unsigned j = k2 >> 1; j > 0; j >>= 1) {
            unsigned i = ((tid & ~(j - 1)) << 1) | (tid & (j - 1));
            unsigned ixj = i | j;
            unsigned long long a = skeys[i], c = skeys[ixj];
            bool desc = ((i & k2) == 0u);
            if (desc ? (a < c) : (a > c)) { skeys[i] = c; skeys[ixj] = a; }
            __syncthreads();
        }
    }

    // ---- prep: decode slot tid, gather box, fill LDS SoA ----
    {
        unsigned long long key = skeys[tid];
        unsigned t = (unsigned)(key >> 22);
        int n = NN - 1 - (int)((key >> 7) & 32767u);
        bkeep[tid] = 0;
        bgi[tid] = (unsigned short)n;
        if (t == 0u) {
            bcls[tid] = 255;
            bsc[tid] = 0.0f;
        } else {
            const float* row = pred + ((size_t)b * NN + n) * 85;
            float x = row[0], y = row[1], w = row[2], h = row[3];
            float vx0 = x - w * 0.5f, vy0 = y - h * 0.5f;
            float vx1 = x + w * 0.5f, vy1 = y + h * 0.5f;
            bx0[tid] = vx0; by0[tid] = vy0; bx1[tid] = vx1; by1[tid] = vy1;
            bar_[tid] = (vx1 - vx0) * (vy1 - vy0);
            bsc[tid] = __uint_as_float(t + TBIAS);  // bit-exact top_s
            bcls[tid] = (unsigned char)(key & 127u);
        }
    }
    __syncthreads();

    // ---- NMS: wave w handles classes {w, w+16, ..., w+64}. Lane owns the
    // 16 slots s === lane (mod 64); alive-bitmask greedy, next survivor via
    // min-reduce. Exactly the reference greedy order (slot order == score
    // order; IoU is translation-invariant so class offsets are unneeded). ----
    {
        const int lane = tid & 63;
        const int wv = tid >> 6;
        unsigned char myc[16];
#pragma unroll
        for (int k = 0; k < 16; ++k) myc[k] = bcls[(k << 6) | lane];

        for (int ci = 0; ci < 5; ++ci) {
            const int c = wv + (ci << 4);
            unsigned alive = 0u;
#pragma unroll
            for (int k = 0; k < 16; ++k)
                if (myc[k] == (unsigned char)c) alive |= (1u << k);
            unsigned keptm = 0u;
            for (;;) {
                int s = alive ? ((__builtin_ctz(alive) << 6) | lane)
                              : (1 << 30);
#pragma unroll
                for (int d = 32; d; d >>= 1) {
                    int o = __shfl_xor(s, d);
                    s = o < s ? o : s;
                }
                if (s >= (1 << 30)) break;  // class exhausted
                if ((s & 63) == lane) {     // owner: keep it
                    alive &= ~(1u << (s >> 6));
                    keptm |= (1u << (s >> 6));
                }
                // broadcast survivor's box (uniform LDS address)
                float ax0 = bx0[s], ay0 = by0[s], ax1 = bx1[s], ay1 = by1[s];
                float aa = bar_[s];
                unsigned rem = alive;
                while (rem) {
                    int k = __builtin_ctz(rem);
                    rem &= rem - 1;
                    int j = (k << 6) | lane;  // all remaining alive are > s
                    float lx = fmaxf(ax0, bx0[j]);
                    float ly = fmaxf(ay0, by0[j]);
                    float rx = fminf(ax1, bx1[j]);
                    float ry = fminf(ay1, by1[j]);
                    float iw = fmaxf(rx - lx, 0.0f);
                    float ih = fmaxf(ry - ly, 0.0f);
                    float inter = iw * ih;
                    float iou = inter / (aa + bar_[j] - inter + 1e-7f);
                    if (iou > IOU_T) alive &= ~(1u << k);
                }
            }
            while (keptm) {
                int k = __builtin_ctz(keptm);
                keptm &= keptm - 1;
                bkeep[(k << 6) | lane] = 1;
            }
        }
    }
    __syncthreads();

    // ---- rank kept rows (inclusive prefix scan) ----
    int kp = (int)bkeep[tid];
    src = sA; dst = sB;
    src[tid] = (unsigned)kp;
    __syncthreads();
    for (int off = 1; off < 1024; off <<= 1) {
        dst[tid] = src[tid] + ((tid >= off) ? src[tid - off] : 0u);
        __syncthreads();
        unsigned* t2 = src; src = dst; dst = t2;
    }
    int rank = (int)src[tid] - kp;
    int kcnt = (int)src[1023];

    // ---- write output rows ----
    if (kp && rank < MAX_DET) {
        int gi = (int)bgi[tid];
        float* orow = out + ((size_t)b * MAX_DET + rank) * 89;
        orow[0] = bx0[tid]; orow[1] = by0[tid];
        orow[2] = bx1[tid]; orow[3] = by1[tid];
        orow[4] = bsc[tid];
        orow[5] = (float)bcls[tid];
        float cl = conf_logits[((size_t)b * NN + gi) * 5 + 4];
        float obj_sig = 1.0f / (1.0f + expf(-cl));
        // logits row is 80 floats = 320 B, always 16B-aligned
        const float4* lrow4 =
            (const float4*)(logits + ((size_t)b * NN + gi) * NCLS);
#pragma unroll 4
        for (int q = 0; q < 20; ++q) {
            float4 l4 = lrow4[q];
            orow[6 + 4 * q + 0] = obj_sig / (1.0f + expf(-l4.x));
            orow[6 + 4 * q + 1] = obj_sig / (1.0f + expf(-l4.y));
            orow[6 + 4 * q + 2] = obj_sig / (1.0f + expf(-l4.z));
            orow[6 + 4 * q + 3] = obj_sig / (1.0f + expf(-l4.w));
        }
        orow[86] = obj_sig;
        orow[87] = head[(size_t)b * NN + gi];
        orow[88] = 1.0f;
    }
    // tail zero-fill: rows [kcnt, 300) are all-zero (replaces d_out memset)
    if (tid < MAX_DET && tid >= kcnt) {
        float* orow = out + ((size_t)b * MAX_DET + tid) * 89;
#pragma unroll
        for (int q = 0; q < 89; ++q) orow[q] = 0.0f;
    }
}

extern "C" void kernel_launch(void* const* d_in, const int* in_sizes, int n_in,
                              void* d_out, int out_size, void* d_ws,
                              size_t ws_size, hipStream_t stream) {
    const float* pred        = (const float*)d_in[0];
    const float* conf_logits = (const float*)d_in[1];
    const float* logits      = (const float*)d_in[2];
    const float* head        = (const float*)d_in[3];
    float* out = (float*)d_out;

    unsigned long long* keys = (unsigned long long*)d_ws;  // 16*25200*8 B

    dim3 sgrid((NN + RROWS - 1) / RROWS, BATCH);
    score_kernel<<<sgrid, STHREADS, 0, stream>>>(pred, keys);
    fused_kernel<<<BATCH, 1024, 0, stream>>>(keys, pred, conf_logits, logits,
                                             head, out);
}

// Round 7
// 346.074 us; speedup vs baseline: 1.0391x; 1.0391x over previous
//
#include <hip/hip_runtime.h>
#include <math.h>

#define BATCH 16
#define NN 25200
#define NCLS 80
#define K_PRE 1024
#define MAX_DET 300
#define CONF_T 0.4f
#define IOU_T 0.45f
#define TBIAS 0x3E000000u
// key layout (47 bits): t(25) << 22 | (NN-1-n)(15) << 7 | cls(7)
// (t, n) is unique, so cls in the low bits never affects sort order.
#define RROWS 128
#define STHREADS 512
#define KITER 25  // ceil(NN / 1024)

// ---------------------------------------------------------------------------
// K1: LDS-staged score + argmax -> 64-bit sort key per row. Pure streaming:
// reads the full 137 MB pred once, coalesced float4. (Unchanged this round —
// next profile will expose its true duration now that K2 is fast.)
// ---------------------------------------------------------------------------
__global__ void __launch_bounds__(STHREADS) score_kernel(
    const float* __restrict__ pred, unsigned long long* __restrict__ keys) {
    __shared__ float srow[RROWS * 85];

    const int tile = blockIdx.x, b = blockIdx.y, tid = threadIdx.x;
    const int row0 = tile * RROWS;
    int nrows = NN - row0;
    if (nrows > RROWS) nrows = RROWS;

    const float4* g4 = (const float4*)(pred + ((size_t)b * NN + row0) * 85);
    float4* l4 = (float4*)srow;
    const int nf4 = (nrows * 85) >> 2;  // nrows % 4 == 0 always
    for (int i = tid; i < nf4; i += STHREADS) l4[i] = g4[i];
    __syncthreads();

    const int r = tid >> 2, sub = tid & 3;
    float best = 0.0f;
    int bc = sub * 20;
    float obj = 0.0f;
    if (r < nrows) {
        obj = srow[r * 85 + 4];
        if (obj > CONF_T) {
            const float* cp = &srow[r * 85 + 5 + sub * 20];
#pragma unroll
            for (int i = 0; i < 20; ++i) {
                float v = cp[i] * obj;
                if (v > best) { best = v; bc = sub * 20 + i; }  // first-max
            }
        }
    }
    // reduce (best, bc) across the 4 lanes of this row, first-max semantics
#pragma unroll
    for (int d = 1; d < 4; d <<= 1) {
        float ov = __shfl_xor(best, d);
        int oc = __shfl_xor(bc, d);
        if (ov > best || (ov == best && oc < bc)) { best = ov; bc = oc; }
    }
    if (r < nrows && sub == 0) {
        unsigned t = (obj > CONF_T && best > CONF_T)
                         ? (__float_as_uint(best) - TBIAS) : 0u;
        int n = row0 + r;
        keys[(size_t)b * NN + n] =
            ((unsigned long long)t << 22) |
            ((unsigned long long)(unsigned)(NN - 1 - n) << 7) | (unsigned)bc;
    }
}

// ---------------------------------------------------------------------------
// K2 (fused v2): per batch. SORT-FREE top-1024:
//   1) all keys -> registers (one global pass, 25 unrolled loads)
//   2) 10-bit digit histogram + suffix scan S (S[d] = #keys with digit >= d)
//   3) contender scatter: keys whose bucket base gt(d)=S[d+1] < 1024 go to
//      LDS slot gt(d) + intra-bucket counter (bucket-grouped layout)
//   4) exact rank = gt(d) + (#greater within own ~40-entry bucket);
//      SoA written directly at slot=rank (ranks unique: keys unique)
//   5) NMS (wave per class, register bitmask greedy) + rank scan + output.
// Replaces d0-select + compact + bitonic-2048: barriers ~90 -> ~26.
// ---------------------------------------------------------------------------
__global__ void __launch_bounds__(1024) fused_kernel(
    const unsigned long long* __restrict__ keys,
    const float* __restrict__ pred,
    const float* __restrict__ conf_logits,
    const float* __restrict__ logits,
    const float* __restrict__ head,
    float* __restrict__ out) {
    __shared__ unsigned sA[1024], sB[1024];        // hist / scan ping-pong
    __shared__ unsigned sBC[1024];                 // per-bucket scatter count
    __shared__ unsigned long long sKeys[2048];     // bucket-grouped contenders
    __shared__ float bx0[K_PRE], by0[K_PRE], bx1[K_PRE], by1[K_PRE],
        bar_[K_PRE], bsc[K_PRE];                   // 24 KB box SoA
    __shared__ unsigned char bcls[K_PRE];          // class (255 = invalid)
    __shared__ unsigned short bgi[K_PRE];          // original row n
    __shared__ unsigned char bkeep[K_PRE];

    const int b = blockIdx.x, tid = threadIdx.x;
    const unsigned long long* bk = keys + (size_t)b * NN;

    // ---- stage this thread's 25 keys into registers (independent loads) ----
    unsigned long long kreg[KITER];
#pragma unroll
    for (int k = 0; k < KITER; ++k) {
        int i = (k << 10) + tid;
        kreg[k] = (i < NN) ? bk[i] : 0ull;
    }

    // ---- digit histogram (from registers) ----
    sA[tid] = 0u;
    sBC[tid] = 0u;
    sKeys[tid] = 0ull;
    sKeys[tid + 1024] = 0ull;
    __syncthreads();
#pragma unroll
    for (int k = 0; k < KITER; ++k) {
        unsigned t = (unsigned)(kreg[k] >> 22);
        if (t) atomicAdd(&sA[t >> 15], 1u);
    }
    __syncthreads();

    // ---- suffix-inclusive scan: S[d] = # keys with digit >= d ----
    unsigned* src = sA;
    unsigned* dst = sB;
    for (int off = 1; off < 1024; off <<= 1) {
        dst[tid] = src[tid] + ((tid + off < 1024) ? src[tid + off] : 0u);
        __syncthreads();
        unsigned* t2 = src; src = dst; dst = t2;
    }
    const unsigned* S = src;  // ends in sA (10 swaps)

    // ---- contender scatter (bucket-grouped) + SoA default init ----
#pragma unroll
    for (int k = 0; k < KITER; ++k) {
        unsigned long long key = kreg[k];
        unsigned t = (unsigned)(key >> 22);
        if (t) {
            unsigned d = t >> 15;
            unsigned base = (d < 1023u) ? S[d + 1] : 0u;  // gt(d)
            if (base < 1024u) {
                unsigned pos = base + atomicAdd(&sBC[d], 1u);
                if (pos < 2048u) sKeys[pos] = key;
            }
        }
    }
    bcls[tid] = 255;
    bsc[tid] = 0.0f;
    bkeep[tid] = 0;
    __syncthreads();

    // ---- exact rank within bucket; write SoA directly at slot=rank ----
#pragma unroll
    for (int half = 0; half < 2; ++half) {
        int i = tid + (half << 10);
        unsigned long long key = sKeys[i];
        if (key) {
            unsigned t = (unsigned)(key >> 22);
            unsigned d = t >> 15;
            unsigned seg = (d < 1023u) ? S[d + 1] : 0u;
            unsigned end = seg + sBC[d];
            if (end > 2048u) end = 2048u;
            unsigned r = seg;
            for (unsigned j = seg; j < end; ++j)
                if (sKeys[j] > key) ++r;
            if (r < 1024u) {
                int n = NN - 1 - (int)((key >> 7) & 32767u);
                const float* row = pred + ((size_t)b * NN + n) * 85;
                float x = row[0], y = row[1], w = row[2], h = row[3];
                float vx0 = x - w * 0.5f, vy0 = y - h * 0.5f;
                float vx1 = x + w * 0.5f, vy1 = y + h * 0.5f;
                bx0[r] = vx0; by0[r] = vy0; bx1[r] = vx1; by1[r] = vy1;
                bar_[r] = (vx1 - vx0) * (vy1 - vy0);
                bsc[r] = __uint_as_float(t + TBIAS);  // bit-exact top_s
                bcls[r] = (unsigned char)(key & 127u);
                bgi[r] = (unsigned short)n;
            }
        }
    }
    __syncthreads();

    // ---- NMS: wave w handles classes {w, w+16, ..., w+64}. Lane owns the
    // 16 slots s === lane (mod 64); alive-bitmask greedy, next survivor via
    // min-reduce. Slot order == global score order, so greedy order matches
    // the reference (IoU is translation-invariant; classes partition slots).
    {
        const int lane = tid & 63;
        const int wv = tid >> 6;
        unsigned char myc[16];
#pragma unroll
        for (int k = 0; k < 16; ++k) myc[k] = bcls[(k << 6) | lane];

        for (int ci = 0; ci < 5; ++ci) {
            const int c = wv + (ci << 4);
            unsigned alive = 0u;
#pragma unroll
            for (int k = 0; k < 16; ++k)
                if (myc[k] == (unsigned char)c) alive |= (1u << k);
            unsigned keptm = 0u;
            for (;;) {
                int s = alive ? ((__builtin_ctz(alive) << 6) | lane)
                              : (1 << 30);
#pragma unroll
                for (int d = 32; d; d >>= 1) {
                    int o = __shfl_xor(s, d);
                    s = o < s ? o : s;
                }
                if (s >= (1 << 30)) break;  // class exhausted
                if ((s & 63) == lane) {     // owner: keep it
                    alive &= ~(1u << (s >> 6));
                    keptm |= (1u << (s >> 6));
                }
                // broadcast survivor's box (uniform LDS address)
                float ax0 = bx0[s], ay0 = by0[s], ax1 = bx1[s], ay1 = by1[s];
                float aa = bar_[s];
                unsigned rem = alive;
                while (rem) {
                    int k = __builtin_ctz(rem);
                    rem &= rem - 1;
                    int j = (k << 6) | lane;  // all remaining alive are > s
                    float lx = fmaxf(ax0, bx0[j]);
                    float ly = fmaxf(ay0, by0[j]);
                    float rx = fminf(ax1, bx1[j]);
                    float ry = fminf(ay1, by1[j]);
                    float iw = fmaxf(rx - lx, 0.0f);
                    float ih = fmaxf(ry - ly, 0.0f);
                    float inter = iw * ih;
                    float iou = inter / (aa + bar_[j] - inter + 1e-7f);
                    if (iou > IOU_T) alive &= ~(1u << k);
                }
            }
            while (keptm) {
                int k = __builtin_ctz(keptm);
                keptm &= keptm - 1;
                bkeep[(k << 6) | lane] = 1;
            }
        }
    }
    __syncthreads();

    // ---- rank kept rows (inclusive prefix scan) ----
    int kp = (int)bkeep[tid];
    src = sA; dst = sB;
    src[tid] = (unsigned)kp;
    __syncthreads();
    for (int off = 1; off < 1024; off <<= 1) {
        dst[tid] = src[tid] + ((tid >= off) ? src[tid - off] : 0u);
        __syncthreads();
        unsigned* t2 = src; src = dst; dst = t2;
    }
    int rank = (int)src[tid] - kp;
    int kcnt = (int)src[1023];

    // ---- write output rows ----
    if (kp && rank < MAX_DET) {
        int gi = (int)bgi[tid];
        float* orow = out + ((size_t)b * MAX_DET + rank) * 89;
        orow[0] = bx0[tid]; orow[1] = by0[tid];
        orow[2] = bx1[tid]; orow[3] = by1[tid];
        orow[4] = bsc[tid];
        orow[5] = (float)bcls[tid];
        float cl = conf_logits[((size_t)b * NN + gi) * 5 + 4];
        float obj_sig = 1.0f / (1.0f + expf(-cl));
        // logits row is 80 floats = 320 B, always 16B-aligned
        const float4* lrow4 =
            (const float4*)(logits + ((size_t)b * NN + gi) * NCLS);
#pragma unroll 4
        for (int q = 0; q < 20; ++q) {
            float4 l4 = lrow4[q];
            orow[6 + 4 * q + 0] = obj_sig / (1.0f + expf(-l4.x));
            orow[6 + 4 * q + 1] = obj_sig / (1.0f + expf(-l4.y));
            orow[6 + 4 * q + 2] = obj_sig / (1.0f + expf(-l4.z));
            orow[6 + 4 * q + 3] = obj_sig / (1.0f + expf(-l4.w));
        }
        orow[86] = obj_sig;
        orow[87] = head[(size_t)b * NN + gi];
        orow[88] = 1.0f;
    }
    // tail zero-fill: rows [kcnt, 300) are all-zero (replaces d_out memset)
    if (tid < MAX_DET && tid >= kcnt) {
        float* orow = out + ((size_t)b * MAX_DET + tid) * 89;
#pragma unroll
        for (int q = 0; q < 89; ++q) orow[q] = 0.0f;
    }
}

extern "C" void kernel_launch(void* const* d_in, const int* in_sizes, int n_in,
                              void* d_out, int out_size, void* d_ws,
                              size_t ws_size, hipStream_t stream) {
    const float* pred        = (const float*)d_in[0];
    const float* conf_logits = (const float*)d_in[1];
    const float* logits      = (const float*)d_in[2];
    const float* head        = (const float*)d_in[3];
    float* out = (float*)d_out;

    unsigned long long* keys = (unsigned long long*)d_ws;  // 16*25200*8 B

    dim3 sgrid((NN + RROWS - 1) / RROWS, BATCH);
    score_kernel<<<sgrid, STHREADS, 0, stream>>>(pred, keys);
    fused_kernel<<<BATCH, 1024, 0, stream>>>(keys, pred, conf_logits, logits,
                                             head, out);
}

// Round 10
// 338.026 us; speedup vs baseline: 1.0638x; 1.0238x over previous
//
#include <hip/hip_runtime.h>
#include <math.h>

#define BATCH 16
#define NN 25200
#define NCLS 80
#define K_PRE 1024
#define MAX_DET 300
#define CONF_T 0.4f
#define IOU_T 0.45f
#define TBIAS 0x3E000000u
// key layout (47 bits): t(25) << 22 | (NN-1-n)(15) << 7 | cls(7)
// (t, n) is unique, so cls in the low bits never affects sort order.
#define RROWS 128
#define KITER 25  // ceil(NN / 1024)

// ---------------------------------------------------------------------------
// K1 (v2): direct-from-global score + argmax -> 64-bit key. No LDS, no
// barrier: thread (r,sub) loads obj + its 20-class chunk (predicated on
// obj>CONF_T, skipping ~40% of class bytes), first-max, 2-step shfl reduce
// across the 4 sub-lanes, one key store per row. 512 thr, 0 LDS ->
// 4 blocks/CU = 32 waves/CU (max occupancy), pure latency-tolerant stream.
// ---------------------------------------------------------------------------
__global__ void __launch_bounds__(512) score_kernel(
    const float* __restrict__ pred, unsigned long long* __restrict__ keys) {
    const int tid = threadIdx.x;
    const int r = tid >> 2, sub = tid & 3;
    const int n = blockIdx.x * RROWS + r;
    const int b = blockIdx.y;

    float best = 0.0f;
    int bc = sub * 20;
    float obj = 0.0f;
    if (n < NN) {
        const float* row = pred + ((size_t)b * NN + n) * 85;
        obj = row[4];
        if (obj > CONF_T) {
            const float* cp = row + 5 + sub * 20;
#pragma unroll
            for (int i = 0; i < 20; ++i) {
                float v = cp[i] * obj;
                if (v > best) { best = v; bc = sub * 20 + i; }  // first-max
            }
        }
    }
    // reduce (best, bc) across the 4 lanes of this row, first-max semantics
#pragma unroll
    for (int d = 1; d < 4; d <<= 1) {
        float ov = __shfl_xor(best, d);
        int oc = __shfl_xor(bc, d);
        if (ov > best || (ov == best && oc < bc)) { best = ov; bc = oc; }
    }
    if (n < NN && sub == 0) {
        unsigned t = (obj > CONF_T && best > CONF_T)
                         ? (__float_as_uint(best) - TBIAS) : 0u;
        keys[(size_t)b * NN + n] =
            ((unsigned long long)t << 22) |
            ((unsigned long long)(unsigned)(NN - 1 - n) << 7) | (unsigned)bc;
    }
}

// ---------------------------------------------------------------------------
// K2 (fused v2, UNCHANGED from round 7 — verified passing): per batch.
// SORT-FREE top-1024: register-staged keys, digit hist + suffix scan,
// bucket-grouped contender scatter, exact intra-bucket rank, LDS SoA,
// wave-per-class bitmask NMS, rank scan, output with tail zero-fill.
// ---------------------------------------------------------------------------
__global__ void __launch_bounds__(1024) fused_kernel(
    const unsigned long long* __restrict__ keys,
    const float* __restrict__ pred,
    const float* __restrict__ conf_logits,
    const float* __restrict__ logits,
    const float* __restrict__ head,
    float* __restrict__ out) {
    __shared__ unsigned sA[1024], sB[1024];        // hist / scan ping-pong
    __shared__ unsigned sBC[1024];                 // per-bucket scatter count
    __shared__ unsigned long long sKeys[2048];     // bucket-grouped contenders
    __shared__ float bx0[K_PRE], by0[K_PRE], bx1[K_PRE], by1[K_PRE],
        bar_[K_PRE], bsc[K_PRE];                   // 24 KB box SoA
    __shared__ unsigned char bcls[K_PRE];          // class (255 = invalid)
    __shared__ unsigned short bgi[K_PRE];          // original row n
    __shared__ unsigned char bkeep[K_PRE];

    const int b = blockIdx.x, tid = threadIdx.x;
    const unsigned long long* bk = keys + (size_t)b * NN;

    // ---- stage this thread's 25 keys into registers (independent loads) ----
    unsigned long long kreg[KITER];
#pragma unroll
    for (int k = 0; k < KITER; ++k) {
        int i = (k << 10) + tid;
        kreg[k] = (i < NN) ? bk[i] : 0ull;
    }

    // ---- digit histogram (from registers) ----
    sA[tid] = 0u;
    sBC[tid] = 0u;
    sKeys[tid] = 0ull;
    sKeys[tid + 1024] = 0ull;
    __syncthreads();
#pragma unroll
    for (int k = 0; k < KITER; ++k) {
        unsigned t = (unsigned)(kreg[k] >> 22);
        if (t) atomicAdd(&sA[t >> 15], 1u);
    }
    __syncthreads();

    // ---- suffix-inclusive scan: S[d] = # keys with digit >= d ----
    unsigned* src = sA;
    unsigned* dst = sB;
    for (int off = 1; off < 1024; off <<= 1) {
        dst[tid] = src[tid] + ((tid + off < 1024) ? src[tid + off] : 0u);
        __syncthreads();
        unsigned* t2 = src; src = dst; dst = t2;
    }
    const unsigned* S = src;  // ends in sA (10 swaps)

    // ---- contender scatter (bucket-grouped) + SoA default init ----
#pragma unroll
    for (int k = 0; k < KITER; ++k) {
        unsigned long long key = kreg[k];
        unsigned t = (unsigned)(key >> 22);
        if (t) {
            unsigned d = t >> 15;
            unsigned base = (d < 1023u) ? S[d + 1] : 0u;  // gt(d)
            if (base < 1024u) {
                unsigned pos = base + atomicAdd(&sBC[d], 1u);
                if (pos < 2048u) sKeys[pos] = key;
            }
        }
    }
    bcls[tid] = 255;
    bsc[tid] = 0.0f;
    bkeep[tid] = 0;
    __syncthreads();

    // ---- exact rank within bucket; write SoA directly at slot=rank ----
#pragma unroll
    for (int half = 0; half < 2; ++half) {
        int i = tid + (half << 10);
        unsigned long long key = sKeys[i];
        if (key) {
            unsigned t = (unsigned)(key >> 22);
            unsigned d = t >> 15;
            unsigned seg = (d < 1023u) ? S[d + 1] : 0u;
            unsigned end = seg + sBC[d];
            if (end > 2048u) end = 2048u;
            unsigned r = seg;
            for (unsigned j = seg; j < end; ++j)
                if (sKeys[j] > key) ++r;
            if (r < 1024u) {
                int n = NN - 1 - (int)((key >> 7) & 32767u);
                const float* row = pred + ((size_t)b * NN + n) * 85;
                float x = row[0], y = row[1], w = row[2], h = row[3];
                float vx0 = x - w * 0.5f, vy0 = y - h * 0.5f;
                float vx1 = x + w * 0.5f, vy1 = y + h * 0.5f;
                bx0[r] = vx0; by0[r] = vy0; bx1[r] = vx1; by1[r] = vy1;
                bar_[r] = (vx1 - vx0) * (vy1 - vy0);
                bsc[r] = __uint_as_float(t + TBIAS);  // bit-exact top_s
                bcls[r] = (unsigned char)(key & 127u);
                bgi[r] = (unsigned short)n;
            }
        }
    }
    __syncthreads();

    // ---- NMS: wave w handles classes {w, w+16, ..., w+64}. Lane owns the
    // 16 slots s === lane (mod 64); alive-bitmask greedy, next survivor via
    // min-reduce. Slot order == global score order, so greedy order matches
    // the reference (IoU is translation-invariant; classes partition slots).
    {
        const int lane = tid & 63;
        const int wv = tid >> 6;
        unsigned char myc[16];
#pragma unroll
        for (int k = 0; k < 16; ++k) myc[k] = bcls[(k << 6) | lane];

        for (int ci = 0; ci < 5; ++ci) {
            const int c = wv + (ci << 4);
            unsigned alive = 0u;
#pragma unroll
            for (int k = 0; k < 16; ++k)
                if (myc[k] == (unsigned char)c) alive |= (1u << k);
            unsigned keptm = 0u;
            for (;;) {
                int s = alive ? ((__builtin_ctz(alive) << 6) | lane)
                              : (1 << 30);
#pragma unroll
                for (int d = 32; d; d >>= 1) {
                    int o = __shfl_xor(s, d);
                    s = o < s ? o : s;
                }
                if (s >= (1 << 30)) break;  // class exhausted
                if ((s & 63) == lane) {     // owner: keep it
                    alive &= ~(1u << (s >> 6));
                    keptm |= (1u << (s >> 6));
                }
                // broadcast survivor's box (uniform LDS address)
                float ax0 = bx0[s], ay0 = by0[s], ax1 = bx1[s], ay1 = by1[s];
                float aa = bar_[s];
                unsigned rem = alive;
                while (rem) {
                    int k = __builtin_ctz(rem);
                    rem &= rem - 1;
                    int j = (k << 6) | lane;  // all remaining alive are > s
                    float lx = fmaxf(ax0, bx0[j]);
                    float ly = fmaxf(ay0, by0[j]);
                    float rx = fminf(ax1, bx1[j]);
                    float ry = fminf(ay1, by1[j]);
                    float iw = fmaxf(rx - lx, 0.0f);
                    float ih = fmaxf(ry - ly, 0.0f);
                    float inter = iw * ih;
                    float iou = inter / (aa + bar_[j] - inter + 1e-7f);
                    if (iou > IOU_T) alive &= ~(1u << k);
                }
            }
            while (keptm) {
                int k = __builtin_ctz(keptm);
                keptm &= keptm - 1;
                bkeep[(k << 6) | lane] = 1;
            }
        }
    }
    __syncthreads();

    // ---- rank kept rows (inclusive prefix scan) ----
    int kp = (int)bkeep[tid];
    src = sA; dst = sB;
    src[tid] = (unsigned)kp;
    __syncthreads();
    for (int off = 1; off < 1024; off <<= 1) {
        dst[tid] = src[tid] + ((tid >= off) ? src[tid - off] : 0u);
        __syncthreads();
        unsigned* t2 = src; src = dst; dst = t2;
    }
    int rank = (int)src[tid] - kp;
    int kcnt = (int)src[1023];

    // ---- write output rows ----
    if (kp && rank < MAX_DET) {
        int gi = (int)bgi[tid];
        float* orow = out + ((size_t)b * MAX_DET + rank) * 89;
        orow[0] = bx0[tid]; orow[1] = by0[tid];
        orow[2] = bx1[tid]; orow[3] = by1[tid];
        orow[4] = bsc[tid];
        orow[5] = (float)bcls[tid];
        float cl = conf_logits[((size_t)b * NN + gi) * 5 + 4];
        float obj_sig = 1.0f / (1.0f + expf(-cl));
        // logits row is 80 floats = 320 B, always 16B-aligned
        const float4* lrow4 =
            (const float4*)(logits + ((size_t)b * NN + gi) * NCLS);
#pragma unroll 4
        for (int q = 0; q < 20; ++q) {
            float4 l4 = lrow4[q];
            orow[6 + 4 * q + 0] = obj_sig / (1.0f + expf(-l4.x));
            orow[6 + 4 * q + 1] = obj_sig / (1.0f + expf(-l4.y));
            orow[6 + 4 * q + 2] = obj_sig / (1.0f + expf(-l4.z));
            orow[6 + 4 * q + 3] = obj_sig / (1.0f + expf(-l4.w));
        }
        orow[86] = obj_sig;
        orow[87] = head[(size_t)b * NN + gi];
        orow[88] = 1.0f;
    }
    // tail zero-fill: rows [kcnt, 300) are all-zero (replaces d_out memset)
    if (tid < MAX_DET && tid >= kcnt) {
        float* orow = out + ((size_t)b * MAX_DET + tid) * 89;
#pragma unroll
        for (int q = 0; q < 89; ++q) orow[q] = 0.0f;
    }
}

extern "C" void kernel_launch(void* const* d_in, const int* in_sizes, int n_in,
                              void* d_out, int out_size, void* d_ws,
                              size_t ws_size, hipStream_t stream) {
    const float* pred        = (const float*)d_in[0];
    const float* conf_logits = (const float*)d_in[1];
    const float* logits      = (const float*)d_in[2];
    const float* head        = (const float*)d_in[3];
    float* out = (float*)d_out;

    unsigned long long* keys = (unsigned long long*)d_ws;  // 16*25200*8 B

    dim3 sgrid((NN + RROWS - 1) / RROWS, BATCH);
    score_kernel<<<sgrid, 512, 0, stream>>>(pred, keys);
    fused_kernel<<<BATCH, 1024, 0, stream>>>(keys, pred, conf_logits, logits,
                                             head, out);
}

// Round 12
// 337.316 us; speedup vs baseline: 1.0661x; 1.0021x over previous
//
#include <hip/hip_runtime.h>
#include <math.h>

#define BATCH 16
#define NN 25200
#define NCLS 80
#define K_PRE 1024
#define MAX_DET 300
#define CONF_T 0.4f
#define IOU_T 0.45f
#define TBIAS 0x3E000000u
// key layout (47 bits): t(25) << 22 | (NN-1-n)(15) << 7 | cls(7)
// (t, n) is unique, so cls in the low bits never affects sort order.
#define RROWS 128
#define KITER 25  // ceil(NN / 1024)

// ---------------------------------------------------------------------------
// K1 (v3): direct-from-global score via VECTORIZED class loads. Thread
// (r,sub) loads its 20-class chunk as 5x float4 (dwordx4 is dword-aligned-
// safe on CDNA; rows are 340 B so chunks are 4B-aligned only). 16 B/lane
// per VMEM instr -> ~4x fewer split transactions than v2's scalar loads
// (the measured 82 us was L1-transaction-bound: 21 instrs x ~64 splits).
// Element order x,y,z,w over i=0..4 == scalar order 0..19: bit-identical
// first-max. No LDS, no barriers, 32 waves/CU.
// ---------------------------------------------------------------------------
__global__ void __launch_bounds__(512) score_kernel(
    const float* __restrict__ pred, unsigned long long* __restrict__ keys) {
    const int tid = threadIdx.x;
    const int r = tid >> 2, sub = tid & 3;
    const int n = blockIdx.x * RROWS + r;
    const int b = blockIdx.y;

    float best = 0.0f;
    int bc = sub * 20;
    float obj = 0.0f;
    if (n < NN) {
        const float* row = pred + ((size_t)b * NN + n) * 85;
        obj = row[4];
        if (obj > CONF_T) {
            const float* cp = row + 5 + sub * 20;
#pragma unroll
            for (int i = 0; i < 5; ++i) {
                float4 v4 = *reinterpret_cast<const float4*>(cp + 4 * i);
                float v;
                v = v4.x * obj;
                if (v > best) { best = v; bc = sub * 20 + 4 * i + 0; }
                v = v4.y * obj;
                if (v > best) { best = v; bc = sub * 20 + 4 * i + 1; }
                v = v4.z * obj;
                if (v > best) { best = v; bc = sub * 20 + 4 * i + 2; }
                v = v4.w * obj;
                if (v > best) { best = v; bc = sub * 20 + 4 * i + 3; }
            }
        }
    }
    // reduce (best, bc) across the 4 lanes of this row, first-max semantics
#pragma unroll
    for (int d = 1; d < 4; d <<= 1) {
        float ov = __shfl_xor(best, d);
        int oc = __shfl_xor(bc, d);
        if (ov > best || (ov == best && oc < bc)) { best = ov; bc = oc; }
    }
    if (n < NN && sub == 0) {
        unsigned t = (obj > CONF_T && best > CONF_T)
                         ? (__float_as_uint(best) - TBIAS) : 0u;
        keys[(size_t)b * NN + n] =
            ((unsigned long long)t << 22) |
            ((unsigned long long)(unsigned)(NN - 1 - n) << 7) | (unsigned)bc;
    }
}

// ---------------------------------------------------------------------------
// K2 (fused v2, UNCHANGED from round 7 — verified passing): per batch.
// SORT-FREE top-1024: register-staged keys, digit hist + suffix scan,
// bucket-grouped contender scatter, exact intra-bucket rank, LDS SoA,
// wave-per-class bitmask NMS, rank scan, output with tail zero-fill.
// ---------------------------------------------------------------------------
__global__ void __launch_bounds__(1024) fused_kernel(
    const unsigned long long* __restrict__ keys,
    const float* __restrict__ pred,
    const float* __restrict__ conf_logits,
    const float* __restrict__ logits,
    const float* __restrict__ head,
    float* __restrict__ out) {
    __shared__ unsigned sA[1024], sB[1024];        // hist / scan ping-pong
    __shared__ unsigned sBC[1024];                 // per-bucket scatter count
    __shared__ unsigned long long sKeys[2048];     // bucket-grouped contenders
    __shared__ float bx0[K_PRE], by0[K_PRE], bx1[K_PRE], by1[K_PRE],
        bar_[K_PRE], bsc[K_PRE];                   // 24 KB box SoA
    __shared__ unsigned char bcls[K_PRE];          // class (255 = invalid)
    __shared__ unsigned short bgi[K_PRE];          // original row n
    __shared__ unsigned char bkeep[K_PRE];

    const int b = blockIdx.x, tid = threadIdx.x;
    const unsigned long long* bk = keys + (size_t)b * NN;

    // ---- stage this thread's 25 keys into registers (independent loads) ----
    unsigned long long kreg[KITER];
#pragma unroll
    for (int k = 0; k < KITER; ++k) {
        int i = (k << 10) + tid;
        kreg[k] = (i < NN) ? bk[i] : 0ull;
    }

    // ---- digit histogram (from registers) ----
    sA[tid] = 0u;
    sBC[tid] = 0u;
    sKeys[tid] = 0ull;
    sKeys[tid + 1024] = 0ull;
    __syncthreads();
#pragma unroll
    for (int k = 0; k < KITER; ++k) {
        unsigned t = (unsigned)(kreg[k] >> 22);
        if (t) atomicAdd(&sA[t >> 15], 1u);
    }
    __syncthreads();

    // ---- suffix-inclusive scan: S[d] = # keys with digit >= d ----
    unsigned* src = sA;
    unsigned* dst = sB;
    for (int off = 1; off < 1024; off <<= 1) {
        dst[tid] = src[tid] + ((tid + off < 1024) ? src[tid + off] : 0u);
        __syncthreads();
        unsigned* t2 = src; src = dst; dst = t2;
    }
    const unsigned* S = src;  // ends in sA (10 swaps)

    // ---- contender scatter (bucket-grouped) + SoA default init ----
#pragma unroll
    for (int k = 0; k < KITER; ++k) {
        unsigned long long key = kreg[k];
        unsigned t = (unsigned)(key >> 22);
        if (t) {
            unsigned d = t >> 15;
            unsigned base = (d < 1023u) ? S[d + 1] : 0u;  // gt(d)
            if (base < 1024u) {
                unsigned pos = base + atomicAdd(&sBC[d], 1u);
                if (pos < 2048u) sKeys[pos] = key;
            }
        }
    }
    bcls[tid] = 255;
    bsc[tid] = 0.0f;
    bkeep[tid] = 0;
    __syncthreads();

    // ---- exact rank within bucket; write SoA directly at slot=rank ----
#pragma unroll
    for (int half = 0; half < 2; ++half) {
        int i = tid + (half << 10);
        unsigned long long key = sKeys[i];
        if (key) {
            unsigned t = (unsigned)(key >> 22);
            unsigned d = t >> 15;
            unsigned seg = (d < 1023u) ? S[d + 1] : 0u;
            unsigned end = seg + sBC[d];
            if (end > 2048u) end = 2048u;
            unsigned r = seg;
            for (unsigned j = seg; j < end; ++j)
                if (sKeys[j] > key) ++r;
            if (r < 1024u) {
                int n = NN - 1 - (int)((key >> 7) & 32767u);
                const float* row = pred + ((size_t)b * NN + n) * 85;
                float x = row[0], y = row[1], w = row[2], h = row[3];
                float vx0 = x - w * 0.5f, vy0 = y - h * 0.5f;
                float vx1 = x + w * 0.5f, vy1 = y + h * 0.5f;
                bx0[r] = vx0; by0[r] = vy0; bx1[r] = vx1; by1[r] = vy1;
                bar_[r] = (vx1 - vx0) * (vy1 - vy0);
                bsc[r] = __uint_as_float(t + TBIAS);  // bit-exact top_s
                bcls[r] = (unsigned char)(key & 127u);
                bgi[r] = (unsigned short)n;
            }
        }
    }
    __syncthreads();

    // ---- NMS: wave w handles classes {w, w+16, ..., w+64}. Lane owns the
    // 16 slots s === lane (mod 64); alive-bitmask greedy, next survivor via
    // min-reduce. Slot order == global score order, so greedy order matches
    // the reference (IoU is translation-invariant; classes partition slots).
    {
        const int lane = tid & 63;
        const int wv = tid >> 6;
        unsigned char myc[16];
#pragma unroll
        for (int k = 0; k < 16; ++k) myc[k] = bcls[(k << 6) | lane];

        for (int ci = 0; ci < 5; ++ci) {
            const int c = wv + (ci << 4);
            unsigned alive = 0u;
#pragma unroll
            for (int k = 0; k < 16; ++k)
                if (myc[k] == (unsigned char)c) alive |= (1u << k);
            unsigned keptm = 0u;
            for (;;) {
                int s = alive ? ((__builtin_ctz(alive) << 6) | lane)
                              : (1 << 30);
#pragma unroll
                for (int d = 32; d; d >>= 1) {
                    int o = __shfl_xor(s, d);
                    s = o < s ? o : s;
                }
                if (s >= (1 << 30)) break;  // class exhausted
                if ((s & 63) == lane) {     // owner: keep it
                    alive &= ~(1u << (s >> 6));
                    keptm |= (1u << (s >> 6));
                }
                // broadcast survivor's box (uniform LDS address)
                float ax0 = bx0[s], ay0 = by0[s], ax1 = bx1[s], ay1 = by1[s];
                float aa = bar_[s];
                unsigned rem = alive;
                while (rem) {
                    int k = __builtin_ctz(rem);
                    rem &= rem - 1;
                    int j = (k << 6) | lane;  // all remaining alive are > s
                    float lx = fmaxf(ax0, bx0[j]);
                    float ly = fmaxf(ay0, by0[j]);
                    float rx = fminf(ax1, bx1[j]);
                    float ry = fminf(ay1, by1[j]);
                    float iw = fmaxf(rx - lx, 0.0f);
                    float ih = fmaxf(ry - ly, 0.0f);
                    float inter = iw * ih;
                    float iou = inter / (aa + bar_[j] - inter + 1e-7f);
                    if (iou > IOU_T) alive &= ~(1u << k);
                }
            }
            while (keptm) {
                int k = __builtin_ctz(keptm);
                keptm &= keptm - 1;
                bkeep[(k << 6) | lane] = 1;
            }
        }
    }
    __syncthreads();

    // ---- rank kept rows (inclusive prefix scan) ----
    int kp = (int)bkeep[tid];
    src = sA; dst = sB;
    src[tid] = (unsigned)kp;
    __syncthreads();
    for (int off = 1; off < 1024; off <<= 1) {
        dst[tid] = src[tid] + ((tid >= off) ? src[tid - off] : 0u);
        __syncthreads();
        unsigned* t2 = src; src = dst; dst = t2;
    }
    int rank = (int)src[tid] - kp;
    int kcnt = (int)src[1023];

    // ---- write output rows ----
    if (kp && rank < MAX_DET) {
        int gi = (int)bgi[tid];
        float* orow = out + ((size_t)b * MAX_DET + rank) * 89;
        orow[0] = bx0[tid]; orow[1] = by0[tid];
        orow[2] = bx1[tid]; orow[3] = by1[tid];
        orow[4] = bsc[tid];
        orow[5] = (float)bcls[tid];
        float cl = conf_logits[((size_t)b * NN + gi) * 5 + 4];
        float obj_sig = 1.0f / (1.0f + expf(-cl));
        // logits row is 80 floats = 320 B, always 16B-aligned
        const float4* lrow4 =
            (const float4*)(logits + ((size_t)b * NN + gi) * NCLS);
#pragma unroll 4
        for (int q = 0; q < 20; ++q) {
            float4 l4 = lrow4[q];
            orow[6 + 4 * q + 0] = obj_sig / (1.0f + expf(-l4.x));
            orow[6 + 4 * q + 1] = obj_sig / (1.0f + expf(-l4.y));
            orow[6 + 4 * q + 2] = obj_sig / (1.0f + expf(-l4.z));
            orow[6 + 4 * q + 3] = obj_sig / (1.0f + expf(-l4.w));
        }
        orow[86] = obj_sig;
        orow[87] = head[(size_t)b * NN + gi];
        orow[88] = 1.0f;
    }
    // tail zero-fill: rows [kcnt, 300) are all-zero (replaces d_out memset)
    if (tid < MAX_DET && tid >= kcnt) {
        float* orow = out + ((size_t)b * MAX_DET + tid) * 89;
#pragma unroll
        for (int q = 0; q < 89; ++q) orow[q] = 0.0f;
    }
}

extern "C" void kernel_launch(void* const* d_in, const int* in_sizes, int n_in,
                              void* d_out, int out_size, void* d_ws,
                              size_t ws_size, hipStream_t stream) {
    const float* pred        = (const float*)d_in[0];
    const float* conf_logits = (const float*)d_in[1];
    const float* logits      = (const float*)d_in[2];
    const float* head        = (const float*)d_in[3];
    float* out = (float*)d_out;

    unsigned long long* keys = (unsigned long long*)d_ws;  // 16*25200*8 B

    dim3 sgrid((NN + RROWS - 1) / RROWS, BATCH);
    score_kernel<<<sgrid, 512, 0, stream>>>(pred, keys);
    fused_kernel<<<BATCH, 1024, 0, stream>>>(keys, pred, conf_logits, logits,
                                             head, out);
}